// Round 9
// baseline (111.564 us; speedup 1.0000x reference)
//
#include <hip/hip_runtime.h>

// AugmentedTripletLoss on MI355X.
// inputs [8192,128] f32, targets [8192] int, center [16,128] f32 -> scalar loss.
//
// v11 = v4's schedule (best-tied at 93us total; 6 sync-structure variants
// v4/v6/v7/v8/v9/v10 all left pairdist at ~32-40us) with the MFMA shape
// swapped 16x16x32 -> 32x32x16:
//   - higher measured ceiling (m119: 2495 vs 2075 TF => 10.3us matrix floor)
//   - HALF the MFMA instruction count per output element -> less issue
//     pressure, longer uninterrupted MFMA blocks for cross-wave hiding.
// Wave owns 64 rows = 2x 32-row tiles; chunk = 32 cols; per chunk:
// 12 ds_read_b128 + 24 MFMA + branchless epilogue. C/D layout col=lane&31,
// row=(r&3)+8*(r>>2)+4*(lane>>5) [m74/m101-verified]; A/B mirror the
// verified 16x16 pattern (row/col=lane&31, k=(lane>>5)*8+j).
// Unchanged: one-hot +-s class bias (K=192, branchless epilogue), T21
// both-sides XOR swizzle, 64-col double-buffered gload_lds stages,
// prep fusion, 16-strip slabs, anti-remat pins, launch_bounds(256,1)
// (v7 precedent: ~210 live regs -> 164 alloc, zero spill).

#define N_ROWS 8192
#define DIM 128
#define KDIM 192          // 128 data dims + 64 one-hot class dims
#define ROWB 384          // KDIM * 2 bytes (bf16)
#define NPROTO 16
#define NSTRIP 16         // 512-col strips
#define MARGIN_F 1.0f
#define EPS_F 1e-12f
#define BIAS_F 32768.0f   // 2*s^2 with s=128 (exact in bf16: 0x4300)

typedef __attribute__((ext_vector_type(8))) short short8;    // 8 bf16
typedef __attribute__((ext_vector_type(16))) float f32x16;   // 32x32 MFMA acc
typedef __attribute__((ext_vector_type(4))) unsigned uint4v;

static __device__ __forceinline__ unsigned f2bf(float f) {
  // round-to-nearest-even bf16 (no NaN expected in this data)
  unsigned u = __float_as_uint(f);
  u += 0x7fffu + ((u >> 16) & 1u);
  return u >> 16;
}

static __device__ __forceinline__ void gload_lds16(const void* g, void* l) {
  __builtin_amdgcn_global_load_lds(
      (const __attribute__((address_space(1))) unsigned*)g,
      (__attribute__((address_space(3))) unsigned*)l, 16, 0, 0);
}

// 512 blocks x 16 rows. Fuses center normalization (redundant per block, 8 KB)
// + row prep: bf16 pack (data + one-hot), ||x||^2, min dist-to-center.
__global__ void prep_kernel(const float* __restrict__ x,
                            const float* __restrict__ center,
                            const int* __restrict__ tgt,
                            char* __restrict__ xbf,
                            float* __restrict__ sq,
                            float* __restrict__ mindc,
                            float* __restrict__ out) {
  __shared__ float scn[NPROTO * DIM];  // normalized prototypes, 8 KB
  int tid = threadIdx.x;
  if (blockIdx.x == 0 && tid == 0) out[0] = 0.0f;  // zero loss accumulator
  int rloc = tid >> 4, l = tid & 15;
  {
    float v[8];
    float ss = 0.f;
#pragma unroll
    for (int j = 0; j < 8; ++j) {
      v[j] = center[rloc * DIM + l * 8 + j];
      ss += v[j] * v[j];
    }
    // 16-lane groups are contiguous in the wave -> masks 1..8 stay in-group
#pragma unroll
    for (int m = 1; m < 16; m <<= 1) ss += __shfl_xor(ss, m, 64);
    float inv = 1.0f / sqrtf(ss);
#pragma unroll
    for (int j = 0; j < 8; ++j) scn[rloc * DIM + l * 8 + j] = v[j] * inv;
  }
  __syncthreads();

  int row = blockIdx.x * 16 + rloc;
  float4 v0 = ((const float4*)x)[row * 32 + l * 2];
  float4 v1 = ((const float4*)x)[row * 32 + l * 2 + 1];
  float ss = v0.x * v0.x + v0.y * v0.y + v0.z * v0.z + v0.w * v0.w +
             v1.x * v1.x + v1.y * v1.y + v1.z * v1.z + v1.w * v1.w;
  float dots[NPROTO];
#pragma unroll
  for (int p = 0; p < NPROTO; ++p) {
    const float* c = &scn[p * DIM + l * 8];
    dots[p] = v0.x * c[0] + v0.y * c[1] + v0.z * c[2] + v0.w * c[3] +
              v1.x * c[4] + v1.y * c[5] + v1.z * c[6] + v1.w * c[7];
  }
#pragma unroll
  for (int m = 1; m < 16; m <<= 1) {
    ss += __shfl_xor(ss, m, 64);
#pragma unroll
    for (int p = 0; p < NPROTO; ++p) dots[p] += __shfl_xor(dots[p], m, 64);
  }
  // data dims: row-major bf16, 384 B/row (first 256 B)
  uint4 pk;
  pk.x = f2bf(v0.x) | (f2bf(v0.y) << 16);
  pk.y = f2bf(v0.z) | (f2bf(v0.w) << 16);
  pk.z = f2bf(v1.x) | (f2bf(v1.y) << 16);
  pk.w = f2bf(v1.z) | (f2bf(v1.w) << 16);
  *(uint4*)(xbf + (size_t)row * ROWB + l * 16) = pk;
  // one-hot class dims (bytes 256..383): -128 (0xC300) at class slot.
  // B side uses the stored -s; A side flips sign in-register -> product -s^2.
  int cls = tgt[row];
  if (l < 8) {
    unsigned wv = (cls & 1) ? 0xC3000000u : 0x0000C300u;  // bf16 -128
    uint4 oh;
    oh.x = ((cls >> 1) == (l * 4 + 0)) ? wv : 0u;
    oh.y = ((cls >> 1) == (l * 4 + 1)) ? wv : 0u;
    oh.z = ((cls >> 1) == (l * 4 + 2)) ? wv : 0u;
    oh.w = ((cls >> 1) == (l * 4 + 3)) ? wv : 0u;
    *(uint4*)(xbf + (size_t)row * ROWB + 256 + l * 16) = oh;
  }
  if (l == 0) {
    float mind2 = INFINITY;
#pragma unroll
    for (int p = 0; p < NPROTO; ++p)
      mind2 = fminf(mind2, ss + 1.0f - 2.0f * dots[p]);  // cn is unit-norm
    sq[row] = ss;
    mindc[row] = fmaxf(sqrtf(fmaxf(mind2, 0.0f)), EPS_F);
  }
}

// Grid: 32 row-groups (256 rows) x 16 strips (512 cols) = 512 blocks.
// Block = 4 waves; wave w owns rows rg*256+w*64..+63 as 2x 32-row MFMA
// tiles; all waves share the LDS-staged B tile (64 cols x 384 B,
// double-buffered; 8 stages x 2 chunks of 32 cols).
// v' = sq_c - 2*dot' tracked; one-hot bias makes positives +32768.
__global__ __launch_bounds__(256, 1) void
pairdist_kernel(const char* __restrict__ xbf, const float* __restrict__ sq,
                float* __restrict__ pmax, float* __restrict__ pmin) {
  __shared__ __align__(16) char bl[2][24576];  // 2 x (64 cols x 384 B)
  const int wave = threadIdx.x >> 6, lane = threadIdx.x & 63;
  const int c31 = lane & 31, h = lane >> 5;
  const int rg = blockIdx.x >> 4, strip = blockIdx.x & 15;
  const int rowbase = rg * 256 + wave * 64;
  const int stripbase = strip * 512;

  // T21 staging offsets (identical to v4): LDS dest linear (base+tid*16);
  // XOR swizzle o' = o ^ ((col&7)<<4) pre-applied to the per-lane GLOBAL
  // source and to the ds_read address (same involution both sides).
  const int slot = threadIdx.x;
  const char* const srcstrip = xbf + (size_t)stripbase * ROWB;
  int soff[6];
#pragma unroll
  for (int r = 0; r < 6; ++r) {
    int o = r * 4096 + slot * 16;
    int c = o / ROWB;
    soff[r] = c * ROWB + ((o - c * ROWB) ^ ((c & 7) << 4));
  }

  auto stage = [&](int s, char* buf) {
    const char* g = srcstrip + (size_t)s * 24576;  // 64 cols * 384 B per stage
#pragma unroll
    for (int r = 0; r < 6; ++r)
      gload_lds16(g + soff[r], buf + r * 4096 + wave * 1024);
  };

  stage(0, bl[0]);  // prefetch stage 0 under the A-fragment loads

  // A-frags for 32x32x16: A[m = lane&31][k = h*8+j], per tile and k-chunk
  // (kc covers k = kc*16..kc*16+15; the 16B at row*384 + kc*32 + h*16).
  // kc 8..11 = one-hot region, stored -s -> flip to +s so product = -s^2.
  short8 a[2][12];
#pragma unroll
  for (int t = 0; t < 2; ++t) {
    const char* ar =
        xbf + (size_t)(rowbase + t * 32 + c31) * ROWB + h * 16;
#pragma unroll
    for (int kc = 0; kc < 12; ++kc) a[t][kc] = *(const short8*)(ar + kc * 32);
#pragma unroll
    for (int kc = 8; kc < 12; ++kc) {
      uint4v u = __builtin_bit_cast(uint4v, a[t][kc]);
      u ^= 0x80008000u;
      a[t][kc] = __builtin_bit_cast(short8, u);
    }
  }
  // anti-remat pin (v5 lesson): asm is the opaque producer -> no global
  // re-load of fragments inside the K-loop.
#pragma unroll
  for (int t = 0; t < 2; ++t)
#pragma unroll
    for (int kc = 0; kc < 12; ++kc)
      asm volatile("" : "+v"(a[t][kc]));

  // Swizzled LDS read offsets for B: lane reads col=c31 (chunk-local),
  // bytes col*384 + kc*32 + h*16, swizzled by (col&7)<<4. Chunk c2 adds
  // c2*32*384 = c2*12288 additively (c2*32 preserves col&7).
  int roff[12];
#pragma unroll
  for (int kc = 0; kc < 12; ++kc)
    roff[kc] = (c31 * ROWB + kc * 32 + h * 16) ^ ((c31 & 7) << 4);

  float maxp[32], minn[32];
#pragma unroll
  for (int i = 0; i < 32; ++i) { maxp[i] = -INFINITY; minn[i] = INFINITY; }

#pragma unroll 1
  for (int s = 0; s < 8; ++s) {
    __syncthreads();  // buf[s&1] staged (vmcnt drain) + prev compute done
    if (s + 1 < 8) stage(s + 1, bl[(s + 1) & 1]);  // lands under compute
    const char* cur = bl[s & 1];
    float sqs[2];  // col ||x||^2 for the two 32-col chunks, hoisted
    sqs[0] = sq[stripbase + s * 64 + c31];
    sqs[1] = sq[stripbase + s * 64 + 32 + c31];
#pragma unroll
    for (int c2 = 0; c2 < 2; ++c2) {
      const char* bufp = cur + c2 * 12288;
      f32x16 acc0 = {}, acc1 = {};
      __builtin_amdgcn_s_setprio(1);  // T5: favor the MFMA cluster
#pragma unroll
      for (int kc = 0; kc < 12; ++kc) {
        short8 b = *(const short8*)(bufp + roff[kc]);
        acc0 = __builtin_amdgcn_mfma_f32_32x32x16_bf16(a[0][kc], b, acc0,
                                                       0, 0, 0);
        acc1 = __builtin_amdgcn_mfma_f32_32x32x16_bf16(a[1][kc], b, acc1,
                                                       0, 0, 0);
      }
      __builtin_amdgcn_s_setprio(0);
      // C/D layout (m74/m101): col = lane&31, row = (r&3)+8*(r>>2)+4*h.
      // Branchless: positives carry +32768 bias, no compare needed.
      float sqc = sqs[c2];
#pragma unroll
      for (int r = 0; r < 16; ++r) {
        float v0 = fmaf(-2.0f, acc0[r], sqc);
        float v1 = fmaf(-2.0f, acc1[r], sqc);
        maxp[r] = fmaxf(maxp[r], v0);
        minn[r] = fminf(minn[r], v0);
        maxp[16 + r] = fmaxf(maxp[16 + r], v1);
        minn[16 + r] = fminf(minn[16 + r], v1);
      }
    }
  }

  // Row stats: reduce across the 32 cols = lanes of each 32-half
  // (masks 1..16 stay within the half: xor of bits 0..4 never crosses bit 5).
#pragma unroll
  for (int m = 1; m < 32; m <<= 1)
#pragma unroll
    for (int i = 0; i < 32; ++i) {
      maxp[i] = fmaxf(maxp[i], __shfl_xor(maxp[i], m, 64));
      minn[i] = fminf(minn[i], __shfl_xor(minn[i], m, 64));
    }
  // lane 0 of each half writes its h's rows: row = t*32 + (r&3)+8*(r>>2)+4*h
  if (c31 == 0) {
    float* pM = pmax + (size_t)strip * N_ROWS + rowbase;
    float* pm = pmin + (size_t)strip * N_ROWS + rowbase;
#pragma unroll
    for (int t = 0; t < 2; ++t)
#pragma unroll
      for (int r = 0; r < 16; ++r) {
        int rowl = t * 32 + (r & 3) + 8 * (r >> 2) + 4 * h;
        pM[rowl] = maxp[t * 16 + r];
        pm[rowl] = minn[t * 16 + r];
      }
  }
}

__global__ void finalize_kernel(const float* __restrict__ pmax,
                                const float* __restrict__ pmin,
                                const float* __restrict__ sq,
                                const float* __restrict__ mindc,
                                float* __restrict__ out) {
  __shared__ float wsum[4];
  int i = blockIdx.x * 256 + threadIdx.x;  // 32 blocks x 256 = 8192 rows
  float maxv = -INFINITY, minv = INFINITY;
#pragma unroll
  for (int s = 0; s < NSTRIP; ++s) {
    maxv = fmaxf(maxv, pmax[s * N_ROWS + i]);
    minv = fminf(minv, pmin[s * N_ROWS + i]);
  }
  float si = sq[i];
  float dap = sqrtf(fmaxf(si + (maxv - BIAS_F), EPS_F));  // un-bias positives
  // negatives are unbiased (< ~2000); if none exist anywhere, minv is the
  // biased positive min (~32768) -> fall back to dap + margin
  float dan = (minv > 16384.0f) ? (dap + MARGIN_F)
                                : sqrtf(fmaxf(si + minv, EPS_F));
  dan = fminf(dan, mindc[i]);
  float c = fmaxf(dap - dan + MARGIN_F, 0.0f) * (1.0f / (float)N_ROWS);
#pragma unroll
  for (int m = 1; m < 64; m <<= 1) c += __shfl_xor(c, m, 64);
  int lane = threadIdx.x & 63, wv = threadIdx.x >> 6;
  if (lane == 0) wsum[wv] = c;
  __syncthreads();
  if (threadIdx.x == 0) atomicAdd(out, wsum[0] + wsum[1] + wsum[2] + wsum[3]);
}

extern "C" void kernel_launch(void* const* d_in, const int* in_sizes, int n_in,
                              void* d_out, int out_size, void* d_ws, size_t ws_size,
                              hipStream_t stream) {
  const float* inputs = (const float*)d_in[0];
  const int* targets = (const int*)d_in[1];  // per harness: integer -> const int*
  const float* center = (const float*)d_in[2];
  char* ws = (char*)d_ws;
  // ws layout (all 256B-aligned):
  char* xbf    = ws;                       // 8192*384 B bf16+onehot = 3 MB
  float* sq    = (float*)(ws + 3145728);   // 8192 f32 = 32 KB
  float* mindc = (float*)(ws + 3178496);   // 8192 f32 = 32 KB
  float* pmax  = (float*)(ws + 3211264);   // 16*8192 f32 = 512 KB
  float* pmin  = (float*)(ws + 3735552);   // 16*8192 f32 = 512 KB
  float* out   = (float*)d_out;

  prep_kernel<<<512, 256, 0, stream>>>(inputs, center, targets, xbf, sq, mindc, out);
  pairdist_kernel<<<512, 256, 0, stream>>>(xbf, sq, pmax, pmin);
  finalize_kernel<<<32, 256, 0, stream>>>(pmax, pmin, sq, mindc, out);
}

// Round 10
// 104.619 us; speedup vs baseline: 1.0664x; 1.0664x over previous
//
#include <hip/hip_runtime.h>

// AugmentedTripletLoss on MI355X.
// inputs [8192,128] f32, targets [8192] int, center [16,128] f32 -> scalar loss.
//
// v12 = v4's verified structure + the ONE untested lever: counted vmcnt
// across the per-stage barrier (T4). v4/v8 sit at the documented m97-family
// plateau (~37% of matrix floor) because __syncthreads drains vmcnt(0)
// every stage; m218 measured counted-vs-drain0 = +38-73%. v9/v10's counted
// attempt failed for a different reason (wave-PRIVATE staging quadrupled
// L2->LDS traffic to ~400MB); here staging stays SHARED (~100MB).
// Mechanics: triple-buffered 64-col stages (3x24KB + 2KB sq = 75.7KB,
// 2 blocks/CU). Stage s top: issue stage s+2's 6 gload_lds. Stage s end:
// s_waitcnt vmcnt(6) (retires s+1's loads, keeps s+2's in flight) + raw
// s_barrier + compiler fence. Per-wave accounting: each wave's vmcnt(6)
// retires its own stage-(s+1) slices; the barrier universalizes (m201's
// safety argument). sq staged to LDS in the prologue so the loop's vmcnt
// carries ONLY staging loads. v11's 32x32 shape reverted (1.57M bank
// conflicts = 8/read); the 16-col q-spread read pattern here measured 0.
// Unchanged from v4 (passed 3x): one-hot +-s class bias (K=192, branchless
// epilogue), T21 both-sides XOR swizzle, A-frag anti-remat pins, prep
// fusion, 16-strip slabs, launch_bounds(256,1) (v7: ~164 VGPR, no spill).

#define N_ROWS 8192
#define DIM 128
#define KDIM 192          // 128 data dims + 64 one-hot class dims
#define ROWB 384          // KDIM * 2 bytes (bf16)
#define NPROTO 16
#define NSTRIP 16         // 512-col strips
#define MARGIN_F 1.0f
#define EPS_F 1e-12f
#define BIAS_F 32768.0f   // 2*s^2 with s=128 (exact in bf16: 0x4300)

typedef __attribute__((ext_vector_type(8))) short short8;   // 8 bf16 = 4 VGPRs
typedef __attribute__((ext_vector_type(4))) float float4v;  // MFMA acc
typedef __attribute__((ext_vector_type(4))) unsigned uint4v;

static __device__ __forceinline__ unsigned f2bf(float f) {
  // round-to-nearest-even bf16 (no NaN expected in this data)
  unsigned u = __float_as_uint(f);
  u += 0x7fffu + ((u >> 16) & 1u);
  return u >> 16;
}

static __device__ __forceinline__ void gload_lds16(const void* g, void* l) {
  __builtin_amdgcn_global_load_lds(
      (const __attribute__((address_space(1))) unsigned*)g,
      (__attribute__((address_space(3))) unsigned*)l, 16, 0, 0);
}

// 512 blocks x 16 rows. Fuses center normalization (redundant per block, 8 KB)
// + row prep: bf16 pack (data + one-hot), ||x||^2, min dist-to-center.
__global__ void prep_kernel(const float* __restrict__ x,
                            const float* __restrict__ center,
                            const int* __restrict__ tgt,
                            char* __restrict__ xbf,
                            float* __restrict__ sq,
                            float* __restrict__ mindc,
                            float* __restrict__ out) {
  __shared__ float scn[NPROTO * DIM];  // normalized prototypes, 8 KB
  int tid = threadIdx.x;
  if (blockIdx.x == 0 && tid == 0) out[0] = 0.0f;  // zero loss accumulator
  int rloc = tid >> 4, l = tid & 15;
  {
    float v[8];
    float ss = 0.f;
#pragma unroll
    for (int j = 0; j < 8; ++j) {
      v[j] = center[rloc * DIM + l * 8 + j];
      ss += v[j] * v[j];
    }
    // 16-lane groups are contiguous in the wave -> masks 1..8 stay in-group
#pragma unroll
    for (int m = 1; m < 16; m <<= 1) ss += __shfl_xor(ss, m, 64);
    float inv = 1.0f / sqrtf(ss);
#pragma unroll
    for (int j = 0; j < 8; ++j) scn[rloc * DIM + l * 8 + j] = v[j] * inv;
  }
  __syncthreads();

  int row = blockIdx.x * 16 + rloc;
  float4 v0 = ((const float4*)x)[row * 32 + l * 2];
  float4 v1 = ((const float4*)x)[row * 32 + l * 2 + 1];
  float ss = v0.x * v0.x + v0.y * v0.y + v0.z * v0.z + v0.w * v0.w +
             v1.x * v1.x + v1.y * v1.y + v1.z * v1.z + v1.w * v1.w;
  float dots[NPROTO];
#pragma unroll
  for (int p = 0; p < NPROTO; ++p) {
    const float* c = &scn[p * DIM + l * 8];
    dots[p] = v0.x * c[0] + v0.y * c[1] + v0.z * c[2] + v0.w * c[3] +
              v1.x * c[4] + v1.y * c[5] + v1.z * c[6] + v1.w * c[7];
  }
#pragma unroll
  for (int m = 1; m < 16; m <<= 1) {
    ss += __shfl_xor(ss, m, 64);
#pragma unroll
    for (int p = 0; p < NPROTO; ++p) dots[p] += __shfl_xor(dots[p], m, 64);
  }
  // data dims: row-major bf16, 384 B/row (first 256 B)
  uint4 pk;
  pk.x = f2bf(v0.x) | (f2bf(v0.y) << 16);
  pk.y = f2bf(v0.z) | (f2bf(v0.w) << 16);
  pk.z = f2bf(v1.x) | (f2bf(v1.y) << 16);
  pk.w = f2bf(v1.z) | (f2bf(v1.w) << 16);
  *(uint4*)(xbf + (size_t)row * ROWB + l * 16) = pk;
  // one-hot class dims (bytes 256..383): -128 (0xC300) at class slot.
  // B side uses the stored -s; A side flips sign in-register -> product -s^2.
  int cls = tgt[row];
  if (l < 8) {
    unsigned wv = (cls & 1) ? 0xC3000000u : 0x0000C300u;  // bf16 -128
    uint4 oh;
    oh.x = ((cls >> 1) == (l * 4 + 0)) ? wv : 0u;
    oh.y = ((cls >> 1) == (l * 4 + 1)) ? wv : 0u;
    oh.z = ((cls >> 1) == (l * 4 + 2)) ? wv : 0u;
    oh.w = ((cls >> 1) == (l * 4 + 3)) ? wv : 0u;
    *(uint4*)(xbf + (size_t)row * ROWB + 256 + l * 16) = oh;
  }
  if (l == 0) {
    float mind2 = INFINITY;
#pragma unroll
    for (int p = 0; p < NPROTO; ++p)
      mind2 = fminf(mind2, ss + 1.0f - 2.0f * dots[p]);  // cn is unit-norm
    sq[row] = ss;
    mindc[row] = fmaxf(sqrtf(fmaxf(mind2, 0.0f)), EPS_F);
  }
}

// Grid: 32 row-groups (256 rows) x 16 strips (512 cols) = 512 blocks.
// Block = 4 waves; wave w owns rows rg*256+w*64..+63 (4 row-tiles); shared
// triple-buffered 64-col stages; 8 stages x 4 phases of 16 cols.
// Counted vmcnt(6) + raw s_barrier per stage (never drain-0 mid-loop).
// v' = sq_c - 2*dot' tracked; one-hot bias makes positives +32768.
__global__ __launch_bounds__(256, 1) void
pairdist_kernel(const char* __restrict__ xbf, const float* __restrict__ sq,
                float* __restrict__ pmax, float* __restrict__ pmin) {
  __shared__ __align__(16) char bl[3][24576];   // 3 x (64 cols x 384 B)
  __shared__ __align__(16) float sqlds[512];    // strip ||x||^2, 2 KB
  const int wave = threadIdx.x >> 6, lane = threadIdx.x & 63;
  const int q = lane >> 4, l16 = lane & 15;
  const int rg = blockIdx.x >> 4, strip = blockIdx.x & 15;
  const int rowbase = rg * 256 + wave * 64;
  const int stripbase = strip * 512;

  // T21 staging offsets: LDS dest linear (base + tid*16); XOR swizzle
  // o' = o ^ ((col&7)<<4) pre-applied to the per-lane GLOBAL source and to
  // the ds_read address below (same involution both sides).
  const int slot = threadIdx.x;
  const char* const srcstrip = xbf + (size_t)stripbase * ROWB;
  int soff[6];
#pragma unroll
  for (int r = 0; r < 6; ++r) {
    int o = r * 4096 + slot * 16;
    int c = o / ROWB;
    soff[r] = c * ROWB + ((o - c * ROWB) ^ ((c & 7) << 4));
  }

  auto stage = [&](int s, char* buf) {
    const char* g = srcstrip + (size_t)s * 24576;  // 64 cols * 384 B
#pragma unroll
    for (int r = 0; r < 6; ++r)
      gload_lds16(g + soff[r], buf + r * 4096 + wave * 1024);
  };

  // A-frags FIRST: their compiler-inserted vmcnt waits land at the pins,
  // BEFORE the staging issue -> they never retire staging loads.
  // A[m=l16][k=q*8+j], 4 row-tiles x 6 k-chunks (last 2 = one-hot, stored
  // -s -> flip to +s so the MFMA product is -s^2).
  short8 a[4][6];
#pragma unroll
  for (int rt = 0; rt < 4; ++rt) {
    const char* ar = xbf + (size_t)(rowbase + rt * 16 + l16) * ROWB + q * 16;
#pragma unroll
    for (int kc = 0; kc < 6; ++kc) a[rt][kc] = *(const short8*)(ar + kc * 64);
#pragma unroll
    for (int kc = 4; kc < 6; ++kc) {
      uint4v u = __builtin_bit_cast(uint4v, a[rt][kc]);
      u ^= 0x80008000u;
      a[rt][kc] = __builtin_bit_cast(short8, u);
    }
  }
#pragma unroll
  for (int rt = 0; rt < 4; ++rt)
#pragma unroll
    for (int kc = 0; kc < 6; ++kc)
      asm volatile("" : "+v"(a[rt][kc]));  // anti-remat pin (v5 lesson)

  // Staging issue: sq (waves 0-1, 1 load), stage 0 (6), stage 1 (6).
  if (wave < 2)
    gload_lds16((const char*)(sq + stripbase) + wave * 1024 + lane * 16,
                (char*)sqlds + wave * 1024 + lane * 16);
  stage(0, bl[0]);
  stage(1, bl[1]);

  // Swizzled LDS read offsets: phase p adds p*6144 additively
  // ((p*16+l16)&7 == l16&7). This 16-col q-spread pattern measured 0 bank
  // conflicts across v4/v8; v11's 32-col pattern (8/read) is reverted.
  int roffb[6];
#pragma unroll
  for (int kc = 0; kc < 6; ++kc)
    roffb[kc] = (l16 * ROWB + kc * 64 + q * 16) ^ ((l16 & 7) << 4);

  float maxp[16], minn[16];
#pragma unroll
  for (int i = 0; i < 16; ++i) { maxp[i] = -INFINITY; minn[i] = INFINITY; }

  // Retire sq + stage 0; keep stage 1's 6 loads in flight across the barrier.
  asm volatile("s_waitcnt vmcnt(6)" ::: "memory");
  __builtin_amdgcn_s_barrier();
  asm volatile("" ::: "memory");  // compiler fence: no ds_read hoisting

#pragma unroll 1
  for (int s = 0; s < 8; ++s) {
    // Issue stage s+2 into bl[(s+2)%3]. Safe: that buffer was last read in
    // stage s-1, and every wave passed the end-of-(s-1) barrier to get here.
    if (s + 2 < 8) stage(s + 2, bl[(s + 2) % 3]);
    const char* cur = bl[s % 3];
#pragma unroll
    for (int p = 0; p < 4; ++p) {
      const char* bufp = cur + p * 6144;
      float sqc = sqlds[s * 64 + p * 16 + l16];  // LDS: off the vmcnt counter
      short8 b[6];
#pragma unroll
      for (int kc = 0; kc < 6; ++kc)
        b[kc] = *(const short8*)(bufp + roffb[kc]);
      float4v acc[4];
#pragma unroll
      for (int rt = 0; rt < 4; ++rt) acc[rt] = (float4v){0.f, 0.f, 0.f, 0.f};
      __builtin_amdgcn_s_setprio(1);  // T5: favor the MFMA cluster
#pragma unroll
      for (int kc = 0; kc < 6; ++kc)
#pragma unroll
        for (int rt = 0; rt < 4; ++rt)  // 4 independent acc chains
          acc[rt] = __builtin_amdgcn_mfma_f32_16x16x32_bf16(a[rt][kc], b[kc],
                                                            acc[rt], 0, 0, 0);
      __builtin_amdgcn_s_setprio(0);
      // C/D layout: col = lane&15, row = q*4 + reg (m89-verified).
      // Branchless: positives carry +32768 bias, no compare needed.
#pragma unroll
      for (int rt = 0; rt < 4; ++rt)
#pragma unroll
        for (int r = 0; r < 4; ++r) {
          float v = fmaf(-2.0f, acc[rt][r], sqc);  // dist2 = sq_row + v
          int idx = rt * 4 + r;
          maxp[idx] = fmaxf(maxp[idx], v);
          minn[idx] = fminf(minn[idx], v);
        }
    }
    // Stage end: retire stage s+1's 6 loads (oldest), keep s+2's 6 in
    // flight. Each wave retires its OWN slices; the barrier universalizes.
    if (s < 7) {
      if (s + 2 < 8)
        asm volatile("s_waitcnt vmcnt(6)" ::: "memory");
      else
        asm volatile("s_waitcnt vmcnt(0)" ::: "memory");
      __builtin_amdgcn_s_barrier();
      asm volatile("" ::: "memory");
    }
  }

  // reduce across the 16 lanes of each quad (xor masks 1..8 stay in-group)
#pragma unroll
  for (int m = 1; m < 16; m <<= 1)
#pragma unroll
    for (int i = 0; i < 16; ++i) {
      maxp[i] = fmaxf(maxp[i], __shfl_xor(maxp[i], m, 64));
      minn[i] = fminf(minn[i], __shfl_xor(minn[i], m, 64));
    }
  // waves own disjoint rows -> no cross-wave reduce; direct scattered store
  if (l16 == 0) {
    float* pM = pmax + (size_t)strip * N_ROWS + rowbase + q * 4;
    float* pm = pmin + (size_t)strip * N_ROWS + rowbase + q * 4;
#pragma unroll
    for (int rt = 0; rt < 4; ++rt)
#pragma unroll
      for (int r = 0; r < 4; ++r) {
        pM[rt * 16 + r] = maxp[rt * 4 + r];
        pm[rt * 16 + r] = minn[rt * 4 + r];
      }
  }
}

__global__ void finalize_kernel(const float* __restrict__ pmax,
                                const float* __restrict__ pmin,
                                const float* __restrict__ sq,
                                const float* __restrict__ mindc,
                                float* __restrict__ out) {
  __shared__ float wsum[4];
  int i = blockIdx.x * 256 + threadIdx.x;  // 32 blocks x 256 = 8192 rows
  float maxv = -INFINITY, minv = INFINITY;
#pragma unroll
  for (int s = 0; s < NSTRIP; ++s) {
    maxv = fmaxf(maxv, pmax[s * N_ROWS + i]);
    minv = fminf(minv, pmin[s * N_ROWS + i]);
  }
  float si = sq[i];
  float dap = sqrtf(fmaxf(si + (maxv - BIAS_F), EPS_F));  // un-bias positives
  // negatives are unbiased (< ~2000); if none exist anywhere, minv is the
  // biased positive min (~32768) -> fall back to dap + margin
  float dan = (minv > 16384.0f) ? (dap + MARGIN_F)
                                : sqrtf(fmaxf(si + minv, EPS_F));
  dan = fminf(dan, mindc[i]);
  float c = fmaxf(dap - dan + MARGIN_F, 0.0f) * (1.0f / (float)N_ROWS);
#pragma unroll
  for (int m = 1; m < 64; m <<= 1) c += __shfl_xor(c, m, 64);
  int lane = threadIdx.x & 63, wv = threadIdx.x >> 6;
  if (lane == 0) wsum[wv] = c;
  __syncthreads();
  if (threadIdx.x == 0) atomicAdd(out, wsum[0] + wsum[1] + wsum[2] + wsum[3]);
}

extern "C" void kernel_launch(void* const* d_in, const int* in_sizes, int n_in,
                              void* d_out, int out_size, void* d_ws, size_t ws_size,
                              hipStream_t stream) {
  const float* inputs = (const float*)d_in[0];
  const int* targets = (const int*)d_in[1];  // per harness: integer -> const int*
  const float* center = (const float*)d_in[2];
  char* ws = (char*)d_ws;
  // ws layout (all 256B-aligned):
  char* xbf    = ws;                       // 8192*384 B bf16+onehot = 3 MB
  float* sq    = (float*)(ws + 3145728);   // 8192 f32 = 32 KB
  float* mindc = (float*)(ws + 3178496);   // 8192 f32 = 32 KB
  float* pmax  = (float*)(ws + 3211264);   // 16*8192 f32 = 512 KB
  float* pmin  = (float*)(ws + 3735552);   // 16*8192 f32 = 512 KB
  float* out   = (float*)d_out;

  prep_kernel<<<512, 256, 0, stream>>>(inputs, center, targets, xbf, sq, mindc, out);
  pairdist_kernel<<<512, 256, 0, stream>>>(xbf, sq, pmax, pmin);
  finalize_kernel<<<32, 256, 0, stream>>>(pmax, pmin, sq, mindc, out);
}

// Round 11
// 95.124 us; speedup vs baseline: 1.1728x; 1.0998x over previous
//
#include <hip/hip_runtime.h>

// AugmentedTripletLoss on MI355X.
// inputs [8192,128] f32, targets [8192] int, center [16,128] f32 -> scalar loss.
//
// v13 = the two proven levers COMBINED for the first time:
//   - v8's TLP: 4 blocks/CU (best total, 91.9us; 2-row-tile waves fit the
//     128-VGPR cap of launch_bounds(256,4) with ~100 live regs, no spill)
//   - v12's counted-vmcnt triple-buffer (only change that raised MfmaUtil,
//     13% -> 21.1%, pairdist 46-50 -> 44.2us measured)
// v12 was stuck at 2 blocks/CU (75.7KB LDS, 4-rt waves can't fit 128 VGPR);
// both pipes sat at 21% = two co-resident waves alternating with nothing to
// fill latency. Here: 3 x 12KB stages + 2KB sq = 38.9KB -> 4 blocks/CU,
// 16 waves/CU, 4 independent barrier groups, AND loads stay in flight
// across barriers (stage s top: issue s+2's 3 gload_lds; stage s end:
// vmcnt(3) retires s+1 only + raw s_barrier; drain-0 only at the tail).
// Unchanged verified pieces: one-hot +-s class bias in the GEMM (K=192,
// branchless epilogue), T21 both-sides XOR swizzle, conflict-free 16-col
// q-spread ds_read pattern, A-frag anti-remat pins, sq staged to LDS
// (vmcnt carries ONLY staging loads), prep fusion, 16-strip slabs.

#define N_ROWS 8192
#define DIM 128
#define KDIM 192          // 128 data dims + 64 one-hot class dims
#define ROWB 384          // KDIM * 2 bytes (bf16)
#define NPROTO 16
#define NSTRIP 16         // 512-col strips
#define NSTAGE 16         // 32-col stages per strip
#define MARGIN_F 1.0f
#define EPS_F 1e-12f
#define BIAS_F 32768.0f   // 2*s^2 with s=128 (exact in bf16: 0x4300)

typedef __attribute__((ext_vector_type(8))) short short8;   // 8 bf16 = 4 VGPRs
typedef __attribute__((ext_vector_type(4))) float float4v;  // MFMA acc
typedef __attribute__((ext_vector_type(4))) unsigned uint4v;

static __device__ __forceinline__ unsigned f2bf(float f) {
  // round-to-nearest-even bf16 (no NaN expected in this data)
  unsigned u = __float_as_uint(f);
  u += 0x7fffu + ((u >> 16) & 1u);
  return u >> 16;
}

static __device__ __forceinline__ void gload_lds16(const void* g, void* l) {
  __builtin_amdgcn_global_load_lds(
      (const __attribute__((address_space(1))) unsigned*)g,
      (__attribute__((address_space(3))) unsigned*)l, 16, 0, 0);
}

// 512 blocks x 16 rows. Fuses center normalization (redundant per block, 8 KB)
// + row prep: bf16 pack (data + one-hot), ||x||^2, min dist-to-center.
__global__ void prep_kernel(const float* __restrict__ x,
                            const float* __restrict__ center,
                            const int* __restrict__ tgt,
                            char* __restrict__ xbf,
                            float* __restrict__ sq,
                            float* __restrict__ mindc,
                            float* __restrict__ out) {
  __shared__ float scn[NPROTO * DIM];  // normalized prototypes, 8 KB
  int tid = threadIdx.x;
  if (blockIdx.x == 0 && tid == 0) out[0] = 0.0f;  // zero loss accumulator
  int rloc = tid >> 4, l = tid & 15;
  {
    float v[8];
    float ss = 0.f;
#pragma unroll
    for (int j = 0; j < 8; ++j) {
      v[j] = center[rloc * DIM + l * 8 + j];
      ss += v[j] * v[j];
    }
    // 16-lane groups are contiguous in the wave -> masks 1..8 stay in-group
#pragma unroll
    for (int m = 1; m < 16; m <<= 1) ss += __shfl_xor(ss, m, 64);
    float inv = 1.0f / sqrtf(ss);
#pragma unroll
    for (int j = 0; j < 8; ++j) scn[rloc * DIM + l * 8 + j] = v[j] * inv;
  }
  __syncthreads();

  int row = blockIdx.x * 16 + rloc;
  float4 v0 = ((const float4*)x)[row * 32 + l * 2];
  float4 v1 = ((const float4*)x)[row * 32 + l * 2 + 1];
  float ss = v0.x * v0.x + v0.y * v0.y + v0.z * v0.z + v0.w * v0.w +
             v1.x * v1.x + v1.y * v1.y + v1.z * v1.z + v1.w * v1.w;
  float dots[NPROTO];
#pragma unroll
  for (int p = 0; p < NPROTO; ++p) {
    const float* c = &scn[p * DIM + l * 8];
    dots[p] = v0.x * c[0] + v0.y * c[1] + v0.z * c[2] + v0.w * c[3] +
              v1.x * c[4] + v1.y * c[5] + v1.z * c[6] + v1.w * c[7];
  }
#pragma unroll
  for (int m = 1; m < 16; m <<= 1) {
    ss += __shfl_xor(ss, m, 64);
#pragma unroll
    for (int p = 0; p < NPROTO; ++p) dots[p] += __shfl_xor(dots[p], m, 64);
  }
  // data dims: row-major bf16, 384 B/row (first 256 B)
  uint4 pk;
  pk.x = f2bf(v0.x) | (f2bf(v0.y) << 16);
  pk.y = f2bf(v0.z) | (f2bf(v0.w) << 16);
  pk.z = f2bf(v1.x) | (f2bf(v1.y) << 16);
  pk.w = f2bf(v1.z) | (f2bf(v1.w) << 16);
  *(uint4*)(xbf + (size_t)row * ROWB + l * 16) = pk;
  // one-hot class dims (bytes 256..383): -128 (0xC300) at class slot.
  // B side uses the stored -s; A side flips sign in-register -> product -s^2.
  int cls = tgt[row];
  if (l < 8) {
    unsigned wv = (cls & 1) ? 0xC3000000u : 0x0000C300u;  // bf16 -128
    uint4 oh;
    oh.x = ((cls >> 1) == (l * 4 + 0)) ? wv : 0u;
    oh.y = ((cls >> 1) == (l * 4 + 1)) ? wv : 0u;
    oh.z = ((cls >> 1) == (l * 4 + 2)) ? wv : 0u;
    oh.w = ((cls >> 1) == (l * 4 + 3)) ? wv : 0u;
    *(uint4*)(xbf + (size_t)row * ROWB + 256 + l * 16) = oh;
  }
  if (l == 0) {
    float mind2 = INFINITY;
#pragma unroll
    for (int p = 0; p < NPROTO; ++p)
      mind2 = fminf(mind2, ss + 1.0f - 2.0f * dots[p]);  // cn is unit-norm
    sq[row] = ss;
    mindc[row] = fmaxf(sqrtf(fmaxf(mind2, 0.0f)), EPS_F);
  }
}

// Grid: 64 row-groups (128 rows) x 16 strips (512 cols) = 1024 blocks
// (exactly 4/CU). Block = 4 waves; wave w owns rows rg*128+w*32..+31
// (2 row-tiles); shared triple-buffered 32-col stages; 16 stages x 2
// phases of 16 cols. Counted vmcnt(3) + raw s_barrier per stage.
// v' = sq_c - 2*dot' tracked; one-hot bias makes positives +32768.
__global__ __launch_bounds__(256, 4) void
pairdist_kernel(const char* __restrict__ xbf, const float* __restrict__ sq,
                float* __restrict__ pmax, float* __restrict__ pmin) {
  __shared__ __align__(16) char bl[3][12288];   // 3 x (32 cols x 384 B)
  __shared__ __align__(16) float sqlds[512];    // strip ||x||^2, 2 KB
  const int wave = threadIdx.x >> 6, lane = threadIdx.x & 63;
  const int q = lane >> 4, l16 = lane & 15;
  const int rg = blockIdx.x >> 4, strip = blockIdx.x & 15;
  const int rowbase = rg * 128 + wave * 32;
  const int stripbase = strip * 512;

  // T21 staging offsets: LDS dest linear (base + tid*16); XOR swizzle
  // o' = o ^ ((col&7)<<4) pre-applied to the per-lane GLOBAL source and to
  // the ds_read address below (same involution both sides).
  const int slot = threadIdx.x;
  const char* const srcstrip = xbf + (size_t)stripbase * ROWB;
  int soff[3];
#pragma unroll
  for (int r = 0; r < 3; ++r) {
    int o = r * 4096 + slot * 16;
    int c = o / ROWB;
    soff[r] = c * ROWB + ((o - c * ROWB) ^ ((c & 7) << 4));
  }

  auto stage = [&](int s, char* buf) {
    const char* g = srcstrip + (size_t)s * 12288;  // 32 cols * 384 B
#pragma unroll
    for (int r = 0; r < 3; ++r)
      gload_lds16(g + soff[r], buf + r * 4096 + wave * 1024);
  };

  // A-frags FIRST: their compiler-inserted vmcnt waits land at the pins,
  // BEFORE the staging issue -> they never retire staging loads.
  // A[m=l16][k=q*8+j], 2 row-tiles x 6 k-chunks (last 2 = one-hot, stored
  // -s -> flip to +s so the MFMA product is -s^2).
  short8 a[2][6];
#pragma unroll
  for (int rt = 0; rt < 2; ++rt) {
    const char* ar = xbf + (size_t)(rowbase + rt * 16 + l16) * ROWB + q * 16;
#pragma unroll
    for (int kc = 0; kc < 6; ++kc) a[rt][kc] = *(const short8*)(ar + kc * 64);
#pragma unroll
    for (int kc = 4; kc < 6; ++kc) {
      uint4v u = __builtin_bit_cast(uint4v, a[rt][kc]);
      u ^= 0x80008000u;
      a[rt][kc] = __builtin_bit_cast(short8, u);
    }
  }
#pragma unroll
  for (int rt = 0; rt < 2; ++rt)
#pragma unroll
    for (int kc = 0; kc < 6; ++kc)
      asm volatile("" : "+v"(a[rt][kc]));  // anti-remat pin (v5 lesson)

  // Staging issue: sq (waves 0-1: 1 load each lane), stage 0 (3), stage 1 (3).
  if (wave < 2)
    gload_lds16((const char*)(sq + stripbase) + wave * 1024 + lane * 16,
                (char*)sqlds + wave * 1024 + lane * 16);
  stage(0, bl[0]);
  stage(1, bl[1]);

  // Swizzled LDS read offsets: phase p adds p*6144 additively
  // ((p*16+l16)&7 == l16&7). This 16-col q-spread pattern measured 0 bank
  // conflicts across v4/v8/v12.
  int roffb[6];
#pragma unroll
  for (int kc = 0; kc < 6; ++kc)
    roffb[kc] = (l16 * ROWB + kc * 64 + q * 16) ^ ((l16 & 7) << 4);

  float maxp[8], minn[8];
#pragma unroll
  for (int i = 0; i < 8; ++i) { maxp[i] = -INFINITY; minn[i] = INFINITY; }

  // Retire sq + stage 0; keep stage 1's 3 loads in flight across the barrier.
  asm volatile("s_waitcnt vmcnt(3)" ::: "memory");
  __builtin_amdgcn_s_barrier();
  asm volatile("" ::: "memory");  // compiler fence: no ds_read hoisting

#pragma unroll 1
  for (int s = 0; s < NSTAGE; ++s) {
    // Issue stage s+2 into bl[(s+2)%3]. Safe: that buffer was last read at
    // stage s-1, and every wave passed the end-of-(s-1) barrier to get here.
    if (s + 2 < NSTAGE) stage(s + 2, bl[(s + 2) % 3]);
    const char* cur = bl[s % 3];
#pragma unroll
    for (int p = 0; p < 2; ++p) {
      const char* bufp = cur + p * 6144;
      float sqc = sqlds[s * 32 + p * 16 + l16];  // LDS: off the vmcnt counter
      short8 b[6];
#pragma unroll
      for (int kc = 0; kc < 6; ++kc)
        b[kc] = *(const short8*)(bufp + roffb[kc]);
      float4v acc[2];
#pragma unroll
      for (int rt = 0; rt < 2; ++rt) acc[rt] = (float4v){0.f, 0.f, 0.f, 0.f};
      __builtin_amdgcn_s_setprio(1);  // T5: favor the MFMA cluster
#pragma unroll
      for (int kc = 0; kc < 6; ++kc)
#pragma unroll
        for (int rt = 0; rt < 2; ++rt)  // 2 independent acc chains
          acc[rt] = __builtin_amdgcn_mfma_f32_16x16x32_bf16(a[rt][kc], b[kc],
                                                            acc[rt], 0, 0, 0);
      __builtin_amdgcn_s_setprio(0);
      // C/D layout: col = lane&15, row = q*4 + reg (m89-verified).
      // Branchless: positives carry +32768 bias, no compare needed.
#pragma unroll
      for (int rt = 0; rt < 2; ++rt)
#pragma unroll
        for (int r = 0; r < 4; ++r) {
          float v = fmaf(-2.0f, acc[rt][r], sqc);  // dist2 = sq_row + v
          int idx = rt * 4 + r;
          maxp[idx] = fmaxf(maxp[idx], v);
          minn[idx] = fminf(minn[idx], v);
        }
    }
    // Stage end: retire stage s+1's 3 loads (oldest), keep s+2's 3 in
    // flight. Each wave retires its OWN slices; the barrier universalizes.
    if (s < NSTAGE - 1) {
      if (s + 2 < NSTAGE)
        asm volatile("s_waitcnt vmcnt(3)" ::: "memory");
      else
        asm volatile("s_waitcnt vmcnt(0)" ::: "memory");
      __builtin_amdgcn_s_barrier();
      asm volatile("" ::: "memory");
    }
  }

  // reduce across the 16 lanes of each quad (xor masks 1..8 stay in-group)
#pragma unroll
  for (int m = 1; m < 16; m <<= 1)
#pragma unroll
    for (int i = 0; i < 8; ++i) {
      maxp[i] = fmaxf(maxp[i], __shfl_xor(maxp[i], m, 64));
      minn[i] = fminf(minn[i], __shfl_xor(minn[i], m, 64));
    }
  // waves own disjoint rows -> no cross-wave reduce; direct scattered store
  if (l16 == 0) {
    float* pM = pmax + (size_t)strip * N_ROWS + rowbase + q * 4;
    float* pm = pmin + (size_t)strip * N_ROWS + rowbase + q * 4;
#pragma unroll
    for (int rt = 0; rt < 2; ++rt)
#pragma unroll
      for (int r = 0; r < 4; ++r) {
        pM[rt * 16 + r] = maxp[rt * 4 + r];
        pm[rt * 16 + r] = minn[rt * 4 + r];
      }
  }
}

__global__ void finalize_kernel(const float* __restrict__ pmax,
                                const float* __restrict__ pmin,
                                const float* __restrict__ sq,
                                const float* __restrict__ mindc,
                                float* __restrict__ out) {
  __shared__ float wsum[4];
  int i = blockIdx.x * 256 + threadIdx.x;  // 32 blocks x 256 = 8192 rows
  float maxv = -INFINITY, minv = INFINITY;
#pragma unroll
  for (int s = 0; s < NSTRIP; ++s) {
    maxv = fmaxf(maxv, pmax[s * N_ROWS + i]);
    minv = fminf(minv, pmin[s * N_ROWS + i]);
  }
  float si = sq[i];
  float dap = sqrtf(fmaxf(si + (maxv - BIAS_F), EPS_F));  // un-bias positives
  // negatives are unbiased (< ~2000); if none exist anywhere, minv is the
  // biased positive min (~32768) -> fall back to dap + margin
  float dan = (minv > 16384.0f) ? (dap + MARGIN_F)
                                : sqrtf(fmaxf(si + minv, EPS_F));
  dan = fminf(dan, mindc[i]);
  float c = fmaxf(dap - dan + MARGIN_F, 0.0f) * (1.0f / (float)N_ROWS);
#pragma unroll
  for (int m = 1; m < 64; m <<= 1) c += __shfl_xor(c, m, 64);
  int lane = threadIdx.x & 63, wv = threadIdx.x >> 6;
  if (lane == 0) wsum[wv] = c;
  __syncthreads();
  if (threadIdx.x == 0) atomicAdd(out, wsum[0] + wsum[1] + wsum[2] + wsum[3]);
}

extern "C" void kernel_launch(void* const* d_in, const int* in_sizes, int n_in,
                              void* d_out, int out_size, void* d_ws, size_t ws_size,
                              hipStream_t stream) {
  const float* inputs = (const float*)d_in[0];
  const int* targets = (const int*)d_in[1];  // per harness: integer -> const int*
  const float* center = (const float*)d_in[2];
  char* ws = (char*)d_ws;
  // ws layout (all 256B-aligned):
  char* xbf    = ws;                       // 8192*384 B bf16+onehot = 3 MB
  float* sq    = (float*)(ws + 3145728);   // 8192 f32 = 32 KB
  float* mindc = (float*)(ws + 3178496);   // 8192 f32 = 32 KB
  float* pmax  = (float*)(ws + 3211264);   // 16*8192 f32 = 512 KB
  float* pmin  = (float*)(ws + 3735552);   // 16*8192 f32 = 512 KB
  float* out   = (float*)d_out;

  prep_kernel<<<512, 256, 0, stream>>>(inputs, center, targets, xbf, sq, mindc, out);
  pairdist_kernel<<<1024, 256, 0, stream>>>(xbf, sq, pmax, pmin);
  finalize_kernel<<<32, 256, 0, stream>>>(pmax, pmin, sq, mindc, out);
}